// Round 7
// baseline (1862.606 us; speedup 1.0000x reference)
//
#include <hip/hip_runtime.h>
#include <math.h>

#define NN 50000
#define TT 16
#define DD 128
#define MT (NN * TT)
#define SCAN_B 1024
#define SCAN_NB ((NN + SCAN_B - 1) / SCAN_B)  // 49

typedef __attribute__((ext_vector_type(8))) short short8;
typedef __attribute__((ext_vector_type(4))) float f32x4;
typedef __attribute__((ext_vector_type(4))) unsigned u32x4;

// ---------- bf16 helpers ----------
static __device__ __forceinline__ unsigned short f2bf(float f) {
  unsigned u = __float_as_uint(f);
  u += 0x7FFFu + ((u >> 16) & 1u);  // RNE
  return (unsigned short)(u >> 16);
}
static __device__ __forceinline__ float bf_lo(unsigned v) {
  return __uint_as_float(v << 16);
}
static __device__ __forceinline__ float bf_hi(unsigned v) {
  return __uint_as_float(v & 0xffff0000u);
}

// ---------- graph preprocessing ----------

__global__ void k_deg_init(int* __restrict__ deg) {
  int i = blockIdx.x * blockDim.x + threadIdx.x;
  if (i < NN) deg[i] = 1;  // self loop
}

__global__ void k_deg_count(const int* __restrict__ dst, int* __restrict__ deg, int e) {
  int i = blockIdx.x * blockDim.x + threadIdx.x;
  if (i < e) atomicAdd(&deg[dst[i]], 1);
}

__global__ void k_dinv(const int* __restrict__ deg, float* __restrict__ dinv) {
  int i = blockIdx.x * blockDim.x + threadIdx.x;
  if (i < NN) dinv[i] = rsqrtf((float)deg[i]);
}

__global__ __launch_bounds__(SCAN_B) void k_scan1(const int* __restrict__ deg,
                                                  int* __restrict__ rowptr,
                                                  int* __restrict__ bsums) {
  __shared__ int sm[SCAN_B];
  int tid = threadIdx.x;
  int i = blockIdx.x * SCAN_B + tid;
  int v = (i < NN) ? (deg[i] - 1) : 0;
  sm[tid] = v;
  __syncthreads();
  for (int off = 1; off < SCAN_B; off <<= 1) {
    int t = (tid >= off) ? sm[tid - off] : 0;
    __syncthreads();
    sm[tid] += t;
    __syncthreads();
  }
  if (i < NN) rowptr[i] = sm[tid] - v;
  if (tid == SCAN_B - 1) bsums[blockIdx.x] = sm[tid];
}

__global__ void k_scan2(int* __restrict__ bsums) {
  __shared__ int sm[64];
  int tid = threadIdx.x;
  int v = (tid < SCAN_NB) ? bsums[tid] : 0;
  sm[tid] = v;
  __syncthreads();
  for (int off = 1; off < 64; off <<= 1) {
    int t = (tid >= off) ? sm[tid - off] : 0;
    __syncthreads();
    sm[tid] += t;
    __syncthreads();
  }
  if (tid < SCAN_NB) bsums[tid] = sm[tid] - v;
  if (tid == 63) bsums[SCAN_NB] = sm[63];
}

__global__ __launch_bounds__(SCAN_B) void k_scan3(int* __restrict__ rowptr,
                                                  const int* __restrict__ bsums) {
  int i = blockIdx.x * SCAN_B + threadIdx.x;
  if (i < NN) rowptr[i] += bsums[blockIdx.x];
  if (i == 0) rowptr[NN] = bsums[SCAN_NB];
}

__global__ void k_fill(const int* __restrict__ src, const int* __restrict__ dst,
                       const int* __restrict__ rowptr, int* __restrict__ cur,
                       int* __restrict__ col, int e) {
  int i = blockIdx.x * blockDim.x + threadIdx.x;
  if (i < e) {
    int d = dst[i];
    int slot = atomicAdd(&cur[d], 1);
    col[rowptr[d] + slot] = src[i];
  }
}

__global__ void k_bsum(const float* __restrict__ bc, const float* __restrict__ bl,
                       float* __restrict__ bsum) {
  int i = threadIdx.x;
  if (i < DD) bsum[i] = bc[i] + bl[i];
}

// W^T bf16 precompute: Wt[n*128+k] = bf16(W[k*128+n]); block = n, thread = k
__global__ void k_wprep(const float* __restrict__ Wc, const float* __restrict__ Wl,
                        unsigned short* __restrict__ Wct, unsigned short* __restrict__ Wlt) {
  int n = blockIdx.x, k = threadIdx.x;
  Wct[n * 128 + k] = f2bf(Wc[k * 128 + n]);
  Wlt[n * 128 + k] = f2bf(Wl[k * 128 + n]);
}

// ---------- GEMM-X (MFMA bf16, swapped operands): Y[row] = bf16((X[row]@Wc)*dinv[row>>4]) ----------
__global__ __launch_bounds__(256) void k_gemmx(
    const float* __restrict__ X, const unsigned short* __restrict__ Wct,
    const float* __restrict__ dinv, unsigned* __restrict__ Yall)
{
  __shared__ unsigned short sA[128 * 136];  // sA[r][k], pad 136
  const int tid = threadIdx.x;
  const long row0 = (long)blockIdx.x * 128;

  // coalesced staging: wave reads 1KB contiguous per instruction
  {
    const float4* xp = (const float4*)(X + row0 * 128);
    #pragma unroll
    for (int it = 0; it < 16; ++it) {
      float4 v = xp[it * 256 + tid];
      int q = it * 256 + tid;          // float4 index in tile
      int r = q >> 5;                  // row = q*4/128
      int k = (q & 31) * 4;            // col
      unsigned u0 = (unsigned)f2bf(v.x) | ((unsigned)f2bf(v.y) << 16);
      unsigned u1 = (unsigned)f2bf(v.z) | ((unsigned)f2bf(v.w) << 16);
      *(uint2*)&sA[r * 136 + k] = make_uint2(u0, u1);
    }
  }
  __syncthreads();

  const int w = tid >> 6, l = tid & 63;
  const int lr = l & 15;
  const int lk = (l >> 4) << 3;
  f32x4 acc[2][8];
  #pragma unroll
  for (int i = 0; i < 2; ++i)
    #pragma unroll
    for (int n = 0; n < 8; ++n) acc[i][n] = (f32x4){0.f, 0.f, 0.f, 0.f};

  #pragma unroll
  for (int kg = 0; kg < 4; ++kg) {
    int kb = kg * 32 + lk;
    short8 a0 = *(const short8*)&sA[(w * 32 + lr) * 136 + kb];
    short8 a1 = *(const short8*)&sA[(w * 32 + 16 + lr) * 136 + kb];
    #pragma unroll
    for (int n = 0; n < 8; ++n) {
      short8 b = *(const short8*)&Wct[(n * 16 + lr) * 128 + kb];
      // swapped: lane holds xrow = l&15, wcol = (l>>4)*4+reg
      acc[0][n] = __builtin_amdgcn_mfma_f32_16x16x32_bf16(b, a0, acc[0][n], 0, 0, 0);
      acc[1][n] = __builtin_amdgcn_mfma_f32_16x16x32_bf16(b, a1, acc[1][n], 0, 0, 0);
    }
  }

  const int wb = (l >> 4) * 4;
  #pragma unroll
  for (int i = 0; i < 2; ++i) {
    long row = row0 + w * 32 + i * 16 + lr;
    float s = dinv[row >> 4];  // row = node*16+t
    #pragma unroll
    for (int n = 0; n < 8; ++n) {
      int c = n * 16 + wb;
      unsigned u0 = (unsigned)f2bf(acc[i][n][0] * s) | ((unsigned)f2bf(acc[i][n][1] * s) << 16);
      unsigned u1 = (unsigned)f2bf(acc[i][n][2] * s) | ((unsigned)f2bf(acc[i][n][3] * s) << 16);
      *(uint2*)(Yall + row * 64 + (c >> 1)) = make_uint2(u0, u1);
    }
  }
}

// ---------- gather: one block per node, all 16 t per edge (4KB coalesced row reads) ----------
// thread tid covers t = tid>>4, d = (tid&15)*8 .. +8  (one uint4 = 8 bf16)
// t==0 lanes fuse step0: out_0 = tanh(agg+bsum), h0 = bf16(out_0). t>=1 -> aggbf.
__global__ __launch_bounds__(256) void k_gatherN(
    const u32x4* __restrict__ Yall,  // [NN][256] u32x4
    const int* __restrict__ col, const int* __restrict__ rowptr,
    const float* __restrict__ dinv, const float* __restrict__ bsum,
    unsigned* __restrict__ aggbf, float* __restrict__ out, unsigned* __restrict__ h0)
{
  const int n = blockIdx.x;
  const int tid = threadIdx.x;
  float a0, a1, a2, a3, a4, a5, a6, a7;
  {
    u32x4 v = Yall[(long)n * 256 + tid];  // self loop
    a0 = bf_lo(v.x); a1 = bf_hi(v.x); a2 = bf_lo(v.y); a3 = bf_hi(v.y);
    a4 = bf_lo(v.z); a5 = bf_hi(v.z); a6 = bf_lo(v.w); a7 = bf_hi(v.w);
  }
  int j = rowptr[n];
  const int end = rowptr[n + 1];
  for (; j + 4 <= end; j += 4) {
    int s0 = col[j], s1 = col[j + 1], s2 = col[j + 2], s3 = col[j + 3];
    u32x4 v0 = Yall[(long)s0 * 256 + tid];
    u32x4 v1 = Yall[(long)s1 * 256 + tid];
    u32x4 v2 = Yall[(long)s2 * 256 + tid];
    u32x4 v3 = Yall[(long)s3 * 256 + tid];
    a0 += bf_lo(v0.x); a1 += bf_hi(v0.x); a2 += bf_lo(v0.y); a3 += bf_hi(v0.y);
    a4 += bf_lo(v0.z); a5 += bf_hi(v0.z); a6 += bf_lo(v0.w); a7 += bf_hi(v0.w);
    a0 += bf_lo(v1.x); a1 += bf_hi(v1.x); a2 += bf_lo(v1.y); a3 += bf_hi(v1.y);
    a4 += bf_lo(v1.z); a5 += bf_hi(v1.z); a6 += bf_lo(v1.w); a7 += bf_hi(v1.w);
    a0 += bf_lo(v2.x); a1 += bf_hi(v2.x); a2 += bf_lo(v2.y); a3 += bf_hi(v2.y);
    a4 += bf_lo(v2.z); a5 += bf_hi(v2.z); a6 += bf_lo(v2.w); a7 += bf_hi(v2.w);
    a0 += bf_lo(v3.x); a1 += bf_hi(v3.x); a2 += bf_lo(v3.y); a3 += bf_hi(v3.y);
    a4 += bf_lo(v3.z); a5 += bf_hi(v3.z); a6 += bf_lo(v3.w); a7 += bf_hi(v3.w);
  }
  for (; j < end; ++j) {
    u32x4 v = Yall[(long)col[j] * 256 + tid];
    a0 += bf_lo(v.x); a1 += bf_hi(v.x); a2 += bf_lo(v.y); a3 += bf_hi(v.y);
    a4 += bf_lo(v.z); a5 += bf_hi(v.z); a6 += bf_lo(v.w); a7 += bf_hi(v.w);
  }
  const float di = dinv[n];
  a0 *= di; a1 *= di; a2 *= di; a3 *= di;
  a4 *= di; a5 *= di; a6 *= di; a7 *= di;
  const int t = tid >> 4, dq = tid & 15;
  if (t == 0) {
    const float4 b0 = *(const float4*)&bsum[dq * 8];
    const float4 b1 = *(const float4*)&bsum[dq * 8 + 4];
    float o0 = tanhf(a0 + b0.x), o1 = tanhf(a1 + b0.y);
    float o2 = tanhf(a2 + b0.z), o3 = tanhf(a3 + b0.w);
    float o4 = tanhf(a4 + b1.x), o5 = tanhf(a5 + b1.y);
    float o6 = tanhf(a6 + b1.z), o7 = tanhf(a7 + b1.w);
    float* op = out + (long)n * (TT * DD) + dq * 8;
    *(float4*)op = make_float4(o0, o1, o2, o3);
    *(float4*)(op + 4) = make_float4(o4, o5, o6, o7);
    u32x4 h;
    h.x = (unsigned)f2bf(o0) | ((unsigned)f2bf(o1) << 16);
    h.y = (unsigned)f2bf(o2) | ((unsigned)f2bf(o3) << 16);
    h.z = (unsigned)f2bf(o4) | ((unsigned)f2bf(o5) << 16);
    h.w = (unsigned)f2bf(o6) | ((unsigned)f2bf(o7) << 16);
    *(u32x4*)(h0 + (long)n * 64 + dq * 4) = h;
  } else {
    u32x4 u;
    u.x = (unsigned)f2bf(a0) | ((unsigned)f2bf(a1) << 16);
    u.y = (unsigned)f2bf(a2) | ((unsigned)f2bf(a3) << 16);
    u.z = (unsigned)f2bf(a4) | ((unsigned)f2bf(a5) << 16);
    u.w = (unsigned)f2bf(a6) | ((unsigned)f2bf(a7) << 16);
    __builtin_nontemporal_store(u, (u32x4*)(aggbf + ((long)n * TT + t) * 64 + dq * 4));
  }
}

// ---------- recurrence GEMM (MFMA bf16): out_t = tanh(h_{t-1}@Wl + agg_t + bsum) ----------
__global__ __launch_bounds__(256) void k_gemmh(
    const unsigned* __restrict__ hprev,      // [NN][64] uints (bf16 h_{t-1})
    const unsigned short* __restrict__ Wlt,  // [n][k] bf16 W_lin^T
    const unsigned* __restrict__ aggbf,
    const float* __restrict__ bsum,
    float* __restrict__ out, unsigned* __restrict__ hnew, int t)
{
  __shared__ unsigned short sA[128 * 136];
  const int tid = threadIdx.x;
  const int row0 = blockIdx.x * 128;

  {
    int r = tid >> 1, half = tid & 1;
    int row = row0 + r;
    const uint4* sp = (const uint4*)(hprev + (long)row * 64 + half * 32);
    unsigned short* dp = &sA[r * 136 + half * 64];
    #pragma unroll
    for (int i = 0; i < 8; ++i) {
      uint4 v = make_uint4(0, 0, 0, 0);
      if (row < NN) v = sp[i];
      *(uint4*)(dp + i * 8) = v;
    }
  }
  __syncthreads();

  const int w = tid >> 6, l = tid & 63;
  const int lr = l & 15;
  const int lk = (l >> 4) << 3;
  f32x4 acc[2][8];
  #pragma unroll
  for (int i = 0; i < 2; ++i)
    #pragma unroll
    for (int n = 0; n < 8; ++n) acc[i][n] = (f32x4){0.f, 0.f, 0.f, 0.f};

  #pragma unroll
  for (int kg = 0; kg < 4; ++kg) {
    int kb = kg * 32 + lk;
    short8 a0 = *(const short8*)&sA[(w * 32 + lr) * 136 + kb];
    short8 a1 = *(const short8*)&sA[(w * 32 + 16 + lr) * 136 + kb];
    #pragma unroll
    for (int n = 0; n < 8; ++n) {
      short8 b = *(const short8*)&Wlt[(n * 16 + lr) * 128 + kb];
      acc[0][n] = __builtin_amdgcn_mfma_f32_16x16x32_bf16(b, a0, acc[0][n], 0, 0, 0);
      acc[1][n] = __builtin_amdgcn_mfma_f32_16x16x32_bf16(b, a1, acc[1][n], 0, 0, 0);
    }
  }

  const int wb = (l >> 4) * 4;
  #pragma unroll
  for (int i = 0; i < 2; ++i) {
    int row = row0 + w * 32 + i * 16 + lr;
    if (row >= NN) continue;
    #pragma unroll
    for (int n = 0; n < 8; ++n) {
      int c = n * 16 + wb;
      uint2 ag = *(const uint2*)(aggbf + ((long)row * TT + t) * 64 + (c >> 1));
      float4 bs = *(const float4*)&bsum[c];
      float o0 = tanhf(acc[i][n][0] + bf_lo(ag.x) + bs.x);
      float o1 = tanhf(acc[i][n][1] + bf_hi(ag.x) + bs.y);
      float o2 = tanhf(acc[i][n][2] + bf_lo(ag.y) + bs.z);
      float o3 = tanhf(acc[i][n][3] + bf_hi(ag.y) + bs.w);
      *(float4*)(out + ((long)row * TT + t) * 128 + c) = make_float4(o0, o1, o2, o3);
      unsigned u0 = (unsigned)f2bf(o0) | ((unsigned)f2bf(o1) << 16);
      unsigned u1 = (unsigned)f2bf(o2) | ((unsigned)f2bf(o3) << 16);
      *(uint2*)(hnew + (long)row * 64 + (c >> 1)) = make_uint2(u0, u1);
    }
  }
}

extern "C" void kernel_launch(void* const* d_in, const int* in_sizes, int n_in,
                              void* d_out, int out_size, void* d_ws, size_t ws_size,
                              hipStream_t stream) {
  const float* x  = (const float*)d_in[0];
  const int*   ei = (const int*)d_in[1];
  const float* Wc = (const float*)d_in[2];
  const float* bc = (const float*)d_in[3];
  const float* Wl = (const float*)d_in[4];
  const float* bl = (const float*)d_in[5];
  float* out = (float*)d_out;
  const int E = in_sizes[1] / 2;
  const int* srcp = ei;
  const int* dstp = ei + E;

  char* w = (char*)d_ws;
  auto alloc = [&](size_t bytes) {
    char* p = w;
    w += (bytes + 255) & ~(size_t)255;
    return p;
  };
  int*            deg    = (int*)alloc(sizeof(int) * NN);
  float*          dinv   = (float*)alloc(sizeof(float) * NN);
  int*            rowptr = (int*)alloc(sizeof(int) * (NN + 1));
  int*            cur    = (int*)alloc(sizeof(int) * NN);
  int*            bsums  = (int*)alloc(sizeof(int) * (SCAN_NB + 1));
  int*            col    = (int*)alloc(sizeof(int) * (size_t)E);
  unsigned*       Yall   = (unsigned*)alloc(sizeof(unsigned) * (size_t)MT * 64);  // 204.8 MB
  unsigned*       aggbf  = (unsigned*)alloc(sizeof(unsigned) * (size_t)MT * 64);  // 204.8 MB
  unsigned*       hbf0   = (unsigned*)alloc(sizeof(unsigned) * (size_t)NN * 64);  // 12.8 MB
  unsigned*       hbf1   = (unsigned*)alloc(sizeof(unsigned) * (size_t)NN * 64);  // 12.8 MB
  float*          bsum   = (float*)alloc(sizeof(float) * DD);
  unsigned short* Wct    = (unsigned short*)alloc(sizeof(unsigned short) * 128 * 128);
  unsigned short* Wlt    = (unsigned short*)alloc(sizeof(unsigned short) * 128 * 128);

  k_deg_init<<<(NN + 255) / 256, 256, 0, stream>>>(deg);
  k_deg_count<<<(E + 255) / 256, 256, 0, stream>>>(dstp, deg, E);
  k_dinv<<<(NN + 255) / 256, 256, 0, stream>>>(deg, dinv);
  k_scan1<<<SCAN_NB, SCAN_B, 0, stream>>>(deg, rowptr, bsums);
  k_scan2<<<1, 64, 0, stream>>>(bsums);
  k_scan3<<<SCAN_NB, SCAN_B, 0, stream>>>(rowptr, bsums);
  (void)hipMemsetAsync(cur, 0, sizeof(int) * NN, stream);
  k_fill<<<(E + 255) / 256, 256, 0, stream>>>(srcp, dstp, rowptr, cur, col, E);
  k_bsum<<<1, 128, 0, stream>>>(bc, bl, bsum);
  k_wprep<<<128, 128, 0, stream>>>(Wc, Wl, Wct, Wlt);

  // Y_all = bf16((x @ Wc) * dinv_src) for all N*T rows
  k_gemmx<<<MT / 128, 256, 0, stream>>>(x, Wct, dinv, Yall);
  // single-pass gather: block per node, 4KB coalesced row reads, step0 fused
  k_gatherN<<<NN, 256, 0, stream>>>((const u32x4*)Yall, col, rowptr, dinv, bsum,
                                    aggbf, out, hbf0);

  for (int t = 1; t < TT; ++t) {
    unsigned* hprev = (t & 1) ? hbf0 : hbf1;
    unsigned* hnew  = (t & 1) ? hbf1 : hbf0;
    k_gemmh<<<(NN + 127) / 128, 256, 0, stream>>>(hprev, Wlt, aggbf, bsum, out, hnew, t);
  }
}